// Round 2
// baseline (617.229 us; speedup 1.0000x reference)
//
#include <hip/hip_runtime.h>
#include <hip/hip_bf16.h>

#define EPSV 1e-5f

typedef __attribute__((ext_vector_type(8))) short short8;
typedef __attribute__((ext_vector_type(4))) float f32x4;

__device__ __forceinline__ int deg_of(int m) {
  return (m == 0) ? 0 : (m < 4 ? 1 : (m < 9 ? 2 : (m < 16 ? 3 : 4)));
}
__device__ __forceinline__ float silu_f(float v) { return v / (1.f + __expf(-v)); }
// round-to-nearest-even f32 -> bf16 bits
__device__ __forceinline__ unsigned short f2bf(float v) {
  unsigned int u = __float_as_uint(v);
  return (unsigned short)((u + 0x7FFFu + ((u >> 16) & 1u)) >> 16);
}
__device__ __forceinline__ short bfs(float v) { return (short)f2bf(v); }

// ---------------- workspace layout (shorts) ----------------
// l1T  [5][64 h][64 c]   @ 0       (20480)   l1T[l][h][c] = l1w[l][c][h]
// l2T  [5][64 o][64 h]   @ 20480   (20480)   l2T[l][o][h] = l2w[l][h][o]
// scT  [64 h][64 c]      @ 40960   (4096)    scT[h][c]    = scw[c][h]
// g1T  [128 o][64 h]     @ 45056   (8192)    g1T[o][h]    = gw1[h][o]
// g2T  [128 o][128 h]    @ 53248   (16384)   g2T[o][h]    = gw2[h][o]
// g3T  [64 o][128 h]     @ 69632   (8192)    g3T[o][h]    = gw3[h][o]
// tgP  [64 s][32 m]      @ 77824   (2048)    zero-padded m>=25
// tgT  [32 m][64 s]      @ 79872   (2048)    zero rows m>=25
// total 81920 shorts = 160 KiB
#define OFF_L1 0
#define OFF_L2 20480
#define OFF_SC 40960
#define OFF_G1 45056
#define OFF_G2 53248
#define OFF_G3 69632
#define OFF_TG 77824
#define OFF_TGT 79872
#define WS_SHORTS 81920

__global__ __launch_bounds__(256) void prep_weights_kernel(
    const float* __restrict__ l1w, const float* __restrict__ l2w,
    const float* __restrict__ scw, const float* __restrict__ gw1,
    const float* __restrict__ gw2, const float* __restrict__ gw3,
    const float* __restrict__ tgm, short* __restrict__ wsh)
{
  int i = blockIdx.x * 256 + threadIdx.x;
  if (i < 20480) {                       // l1T
    int l = i >> 12, r = i & 4095, h = r >> 6, c = r & 63;
    wsh[i] = bfs(l1w[l * 4096 + c * 64 + h]);
  } else if (i < 40960) {                // l2T
    int r0 = i - OFF_L2;
    int l = r0 >> 12, r = r0 & 4095, o = r >> 6, h = r & 63;
    wsh[i] = bfs(l2w[l * 4096 + h * 64 + o]);
  } else if (i < 45056) {                // scT
    int r = i - OFF_SC, h = r >> 6, c = r & 63;
    wsh[i] = bfs(scw[c * 64 + h]);
  } else if (i < 53248) {                // g1T
    int r = i - OFF_G1, o = r >> 6, h = r & 63;
    wsh[i] = bfs(gw1[h * 128 + o]);
  } else if (i < 69632) {                // g2T
    int r = i - OFF_G2, o = r >> 7, h = r & 127;
    wsh[i] = bfs(gw2[h * 128 + o]);
  } else if (i < 77824) {                // g3T
    int r = i - OFF_G3, o = r >> 7, h = r & 127;
    wsh[i] = bfs(gw3[h * 64 + o]);
  } else if (i < 79872) {                // tgP [64][32], pad m>=25
    int r = i - OFF_TG, s = r >> 5, m = r & 31;
    wsh[i] = (m < 25) ? bfs(tgm[s * 25 + m]) : (short)0;
  } else if (i < WS_SHORTS) {            // tgT [32][64], zero rows m>=25
    int r = i - OFF_TGT, m = r >> 6, s = r & 63;
    wsh[i] = (m < 25) ? bfs(tgm[s * 25 + m]) : (short)0;
  }
}

// LDS layout (float indices), 9856 floats = 39,424 B -> 4 blocks/CU.
// Region A [0,4352):   XB f32 [25][68] (ph0-1b) -> T1u bf16 [64][136] (ph4-5)
//                      -> G3u bf16 [64][72] (ph6-7)
// Region B [4352,8704): XBh bf16 [32][72] @4352 (1b-3), H1u bf16 [64][40] @5504 (3-3b),
//                       GBu bf16 [64][72] @6784 (3b-4)  -> T2u bf16 [64][136] @4352 (5-6)
// Region C [8704,9856): RD f32 [256] (ph1) -> HBh bf16 [32][72] (ph7-8)

__global__ __launch_bounds__(256, 4) void fused_sample_kernel(
    const float* __restrict__ x,
    const float* __restrict__ nl0w, const float* __restrict__ nl0b,
    const float* __restrict__ affw,
    const float* __restrict__ l1b,
    const float* __restrict__ scb,
    const float* __restrict__ l2b,
    const short* __restrict__ wsh,
    float* __restrict__ out, int nTot)
{
  __shared__ float sm[9856];
  float*          XB  = sm;                                   // [25][68] f32
  unsigned short* T1u = (unsigned short*)sm;                  // [64][136]
  unsigned short* G3u = (unsigned short*)sm;                  // [64][72]
  unsigned short* XBh = (unsigned short*)(sm + 4352);         // [32][72]
  unsigned short* H1u = (unsigned short*)(sm + 5504);         // [64][40]
  unsigned short* GBu = (unsigned short*)(sm + 6784);         // [64][72]
  unsigned short* T2u = (unsigned short*)(sm + 4352);         // [64][136]
  float*          RD  = sm + 8704;                            // [256]
  unsigned short* HBh = (unsigned short*)(sm + 8704);         // [32][72]

  const int t = threadIdx.x;
  const int n = blockIdx.x;
  if (n >= nTot) return;

  const int W    = t >> 6;
  const int lane = t & 63;
  const int quad = lane >> 4;
  const int l16  = lane & 15;
  const int hcol = W * 16 + l16;   // this wave's output column

  const float* gx = x + (size_t)n * 1600;
  const short8 z8 = (short8){0,0,0,0,0,0,0,0};

  const short* l1T = wsh + OFF_L1;
  const short* l2T = wsh + OFF_L2;
  const short* scT = wsh + OFF_SC;
  const short* g1T = wsh + OFF_G1;
  const short* g2T = wsh + OFF_G2;
  const short* g3T = wsh + OFF_G3;
  const short* tgP = wsh + OFF_TG;
  const short* tgT = wsh + OFF_TGT;

  // ---- phase 0: stage x -> XB f32; zero H1u k-pad cols 25..31 (dead region) ----
  for (int f = 4 * t; f < 1600; f += 1024) {
    float4 v = *(const float4*)(gx + f);
    int m = f >> 6, c = f & 63;
    *(float4*)(XB + m * 68 + c) = v;
  }
  for (int i = t; i < 448; i += 256) {
    int r = i / 7, k = 25 + i % 7;
    H1u[r * 40 + k] = 0;
  }
  __syncthreads();

  // ---- phase 1: norms ----
  {
    float part = 0.f;
    for (int f = 64 + t; f < 1600; f += 256) {
      int m = f >> 6, c = f & 63;
      float v = XB[m * 68 + c];
      int l = deg_of(m);
      part += v * v * (1.f / (float)((2 * l + 1) * 4));
    }
    RD[t] = part;
  }
  __syncthreads();
  if (t < 64) {
    float s4 = RD[t] + RD[t + 64] + RD[t + 128] + RD[t + 192];
    #pragma unroll
    for (int o = 32; o >= 1; o >>= 1) s4 += __shfl_xor(s4, o, 64);
    if (t == 0) RD[0] = rsqrtf(s4 * (1.f / 64.f) + EPSV);
  } else if (t < 128) {
    int c = t - 64;
    float v = XB[c];
    float s1 = v, s2 = v * v;
    #pragma unroll
    for (int o = 32; o >= 1; o >>= 1) {
      s1 += __shfl_xor(s1, o, 64);
      s2 += __shfl_xor(s2, o, 64);
    }
    float mu  = s1 * (1.f / 64.f);
    float var = s2 * (1.f / 64.f) - mu * mu;
    XB[c] = (v - mu) * rsqrtf(var + EPSV) * nl0w[c] + nl0b[c];
  }
  __syncthreads();

  // ---- phase 1b: xn -> bf16 (XBh); PREFETCH phase-3 weight fragments ----
  short8 B3[12];  // [l*2+ks] for l1w, [10+ks] for scw — loads overlap ph1b + barrier
  {
    #pragma unroll
    for (int l = 0; l < 5; ++l)
      #pragma unroll
      for (int ks = 0; ks < 2; ++ks)
        B3[l * 2 + ks] = *(const short8*)(l1T + l * 4096 + hcol * 64 + ks * 32 + quad * 8);
    #pragma unroll
    for (int ks = 0; ks < 2; ++ks)
      B3[10 + ks] = *(const short8*)(scT + hcol * 64 + ks * 32 + quad * 8);

    float inv = RD[0];
    for (int f = t; f < 1600; f += 256) {
      int m = f >> 6, c = f & 63;
      float v = XB[m * 68 + c];
      if (m > 0) v *= inv * affw[(deg_of(m) - 1) * 64 + c];
      XBh[m * 72 + c] = f2bf(v);
    }
  }
  __syncthreads();

  // ---- phase 3 (MFMA): h1 = xn @ lin1_w[deg]; gating = silu(xn0@scw+scb) ----
  float gval;
  short8 tg3b;    // prefetched for phase 3b
  {
    tg3b = *(const short8*)(tgP + (W * 16 + l16) * 32 + quad * 8);

    short8 a0[2], a1[2];
    #pragma unroll
    for (int ks = 0; ks < 2; ++ks) {
      a0[ks] = *(const short8*)(XBh + l16 * 72 + ks * 32 + quad * 8);
      a1[ks] = *(const short8*)(XBh + (16 + l16) * 72 + ks * 32 + quad * 8);
    }
    const int dl = deg_of(l16);
    f32x4 c0 = (f32x4){0,0,0,0}, c1 = (f32x4){0,0,0,0}, cg = (f32x4){0,0,0,0};
    #pragma unroll
    for (int ks = 0; ks < 2; ++ks) {
      #pragma unroll
      for (int l = 0; l < 4; ++l) {
        short8 am = (dl == l) ? a0[ks] : z8;
        c0 = __builtin_amdgcn_mfma_f32_16x16x32_bf16(am, B3[l * 2 + ks], c0, 0, 0, 0);
      }
      c1 = __builtin_amdgcn_mfma_f32_16x16x32_bf16(a1[ks], B3[8 + ks], c1, 0, 0, 0);
      short8 ag = (l16 == 0) ? a0[ks] : z8;
      cg = __builtin_amdgcn_mfma_f32_16x16x32_bf16(ag, B3[10 + ks], cg, 0, 0, 0);
    }
    // D-writes: h1 transposed -> H1u[h][m], bias on m==0
    #pragma unroll
    for (int r = 0; r < 4; ++r) {
      int m = quad * 4 + r;
      float v = c0[r] + ((m == 0) ? l1b[hcol] : 0.f);
      H1u[hcol * 40 + m] = f2bf(v);
    }
    #pragma unroll
    for (int r = 0; r < 4; ++r) {
      int m = 16 + quad * 4 + r;
      if (m < 25) H1u[hcol * 40 + m] = f2bf(c1[r]);
    }
    gval = silu_f(cg[0] + scb[hcol]);  // valid on quad==0 lanes (row 0)
  }
  __syncthreads();

  // ---- phase 3b (MFMA): g = to_grid @ h1; PREFETCH phase-4 weights ----
  short8 bf4[4];
  {
    #pragma unroll
    for (int nt2 = 0; nt2 < 2; ++nt2)
      #pragma unroll
      for (int ks = 0; ks < 2; ++ks)
        bf4[nt2 * 2 + ks] = *(const short8*)(g1T + ((2 * W + nt2) * 16 + l16) * 64 + ks * 32 + quad * 8);

    f32x4 cg3[4];
    #pragma unroll
    for (int nt = 0; nt < 4; ++nt) cg3[nt] = (f32x4){0,0,0,0};
    #pragma unroll
    for (int nt = 0; nt < 4; ++nt) {
      short8 b = *(const short8*)(H1u + (nt * 16 + l16) * 40 + quad * 8);
      cg3[nt] = __builtin_amdgcn_mfma_f32_16x16x32_bf16(tg3b, b, cg3[nt], 0, 0, 0);
    }
    #pragma unroll
    for (int nt = 0; nt < 4; ++nt)
      #pragma unroll
      for (int r = 0; r < 4; ++r) {
        int s = W * 16 + quad * 4 + r;
        GBu[s * 72 + nt * 16 + l16] = f2bf(cg3[nt][r]);
      }
  }
  __syncthreads();

  // ---- phase 4 (MFMA): t1 = silu(g @ w1), 64x64 @ 64x128; PREFETCH ph5 ----
  short8 bf5[8];
  {
    #pragma unroll
    for (int nt2 = 0; nt2 < 2; ++nt2)
      #pragma unroll
      for (int ks = 0; ks < 4; ++ks)
        bf5[nt2 * 4 + ks] = *(const short8*)(g2T + ((2 * W + nt2) * 16 + l16) * 128 + ks * 32 + quad * 8);

    f32x4 acc[8];
    #pragma unroll
    for (int i = 0; i < 8; ++i) acc[i] = (f32x4){0,0,0,0};
    #pragma unroll
    for (int mt = 0; mt < 4; ++mt)
      #pragma unroll
      for (int ks = 0; ks < 2; ++ks) {
        short8 a = *(const short8*)(GBu + (mt * 16 + l16) * 72 + ks * 32 + quad * 8);
        acc[mt * 2 + 0] = __builtin_amdgcn_mfma_f32_16x16x32_bf16(a, bf4[ks],     acc[mt * 2 + 0], 0, 0, 0);
        acc[mt * 2 + 1] = __builtin_amdgcn_mfma_f32_16x16x32_bf16(a, bf4[2 + ks], acc[mt * 2 + 1], 0, 0, 0);
      }
    #pragma unroll
    for (int mt = 0; mt < 4; ++mt)
      #pragma unroll
      for (int nt2 = 0; nt2 < 2; ++nt2) {
        int col = (2 * W + nt2) * 16 + l16;
        #pragma unroll
        for (int r = 0; r < 4; ++r) {
          int srow = mt * 16 + quad * 4 + r;
          T1u[srow * 136 + col] = f2bf(silu_f(acc[mt * 2 + nt2][r]));
        }
      }
  }
  __syncthreads();

  // ---- phase 5 (MFMA): t2 = silu(t1 @ w2), 64x128 @ 128x128; PREFETCH ph6 ----
  short8 bf6[4];
  {
    #pragma unroll
    for (int ks = 0; ks < 4; ++ks)
      bf6[ks] = *(const short8*)(g3T + hcol * 128 + ks * 32 + quad * 8);

    f32x4 acc[8];
    #pragma unroll
    for (int i = 0; i < 8; ++i) acc[i] = (f32x4){0,0,0,0};
    #pragma unroll
    for (int mt = 0; mt < 4; ++mt)
      #pragma unroll
      for (int ks = 0; ks < 4; ++ks) {
        short8 a = *(const short8*)(T1u + (mt * 16 + l16) * 136 + ks * 32 + quad * 8);
        acc[mt * 2 + 0] = __builtin_amdgcn_mfma_f32_16x16x32_bf16(a, bf5[ks],     acc[mt * 2 + 0], 0, 0, 0);
        acc[mt * 2 + 1] = __builtin_amdgcn_mfma_f32_16x16x32_bf16(a, bf5[4 + ks], acc[mt * 2 + 1], 0, 0, 0);
      }
    #pragma unroll
    for (int mt = 0; mt < 4; ++mt)
      #pragma unroll
      for (int nt2 = 0; nt2 < 2; ++nt2) {
        int col = (2 * W + nt2) * 16 + l16;
        #pragma unroll
        for (int r = 0; r < 4; ++r) {
          int srow = mt * 16 + quad * 4 + r;
          T2u[srow * 136 + col] = f2bf(silu_f(acc[mt * 2 + nt2][r]));
        }
      }
  }
  __syncthreads();

  // ---- phase 6 (MFMA): g3 = t2 @ w3, store transposed; PREFETCH ph7 ----
  short8 a7[2][2];
  {
    #pragma unroll
    for (int mt = 0; mt < 2; ++mt)
      #pragma unroll
      for (int ks = 0; ks < 2; ++ks)
        a7[mt][ks] = *(const short8*)(tgT + (mt * 16 + l16) * 64 + ks * 32 + quad * 8);

    f32x4 acc[4];
    #pragma unroll
    for (int i = 0; i < 4; ++i) acc[i] = (f32x4){0,0,0,0};
    #pragma unroll
    for (int mt = 0; mt < 4; ++mt)
      #pragma unroll
      for (int ks = 0; ks < 4; ++ks) {
        short8 a = *(const short8*)(T2u + (mt * 16 + l16) * 136 + ks * 32 + quad * 8);
        acc[mt] = __builtin_amdgcn_mfma_f32_16x16x32_bf16(a, bf6[ks], acc[mt], 0, 0, 0);
      }
    #pragma unroll
    for (int mt = 0; mt < 4; ++mt)
      #pragma unroll
      for (int r = 0; r < 4; ++r) {
        int s = mt * 16 + quad * 4 + r;
        G3u[hcol * 72 + s] = f2bf(acc[mt][r]);
      }
  }
  __syncthreads();

  // ---- phase 7 (MFMA): hb = to_grid^T @ g3 (rows 1..24); PREFETCH ph8 ----
  short8 B8[10];
  {
    #pragma unroll
    for (int l = 0; l < 5; ++l)
      #pragma unroll
      for (int ks = 0; ks < 2; ++ks)
        B8[l * 2 + ks] = *(const short8*)(l2T + l * 4096 + hcol * 64 + ks * 32 + quad * 8);

    short8 b7[2];
    #pragma unroll
    for (int ks = 0; ks < 2; ++ks)
      b7[ks] = *(const short8*)(G3u + hcol * 72 + ks * 32 + quad * 8);
    f32x4 c7[2];
    #pragma unroll
    for (int mt = 0; mt < 2; ++mt) c7[mt] = (f32x4){0,0,0,0};
    #pragma unroll
    for (int mt = 0; mt < 2; ++mt)
      #pragma unroll
      for (int ks = 0; ks < 2; ++ks)
        c7[mt] = __builtin_amdgcn_mfma_f32_16x16x32_bf16(a7[mt][ks], b7[ks], c7[mt], 0, 0, 0);
    #pragma unroll
    for (int mt = 0; mt < 2; ++mt)
      #pragma unroll
      for (int r = 0; r < 4; ++r) {
        int m = mt * 16 + quad * 4 + r;
        if (m >= 1 && m < 25) HBh[m * 72 + hcol] = f2bf(c7[mt][r]);
      }
    if (quad == 0) HBh[hcol] = f2bf(gval);
  }
  __syncthreads();

  // ---- phase 8 (MFMA): out = hb @ lin2_w[deg] (+ lin2_b on row 0) ----
  {
    short8 a0[2], a1[2];
    #pragma unroll
    for (int ks = 0; ks < 2; ++ks) {
      a0[ks] = *(const short8*)(HBh + l16 * 72 + ks * 32 + quad * 8);
      a1[ks] = *(const short8*)(HBh + (16 + l16) * 72 + ks * 32 + quad * 8);
    }
    const int dl = deg_of(l16);
    f32x4 c0 = (f32x4){0,0,0,0}, c1 = (f32x4){0,0,0,0};
    #pragma unroll
    for (int ks = 0; ks < 2; ++ks) {
      #pragma unroll
      for (int l = 0; l < 4; ++l) {
        short8 am = (dl == l) ? a0[ks] : z8;
        c0 = __builtin_amdgcn_mfma_f32_16x16x32_bf16(am, B8[l * 2 + ks], c0, 0, 0, 0);
      }
      c1 = __builtin_amdgcn_mfma_f32_16x16x32_bf16(a1[ks], B8[8 + ks], c1, 0, 0, 0);
    }
    float* go = out + (size_t)n * 1600;
    float bias = l2b[hcol];
    #pragma unroll
    for (int r = 0; r < 4; ++r) {
      int m = quad * 4 + r;
      go[m * 64 + hcol] = c0[r] + ((m == 0) ? bias : 0.f);
    }
    #pragma unroll
    for (int r = 0; r < 4; ++r) {
      int m = 16 + quad * 4 + r;
      if (m < 25) go[m * 64 + hcol] = c1[r];
    }
  }
}

extern "C" void kernel_launch(void* const* d_in, const int* in_sizes, int n_in,
                              void* d_out, int out_size, void* d_ws, size_t ws_size,
                              hipStream_t stream) {
  const float* x    = (const float*)d_in[0];
  const float* nl0w = (const float*)d_in[1];
  const float* nl0b = (const float*)d_in[2];
  const float* affw = (const float*)d_in[3];
  const float* l1w  = (const float*)d_in[4];
  const float* l1b  = (const float*)d_in[5];
  const float* scw  = (const float*)d_in[6];
  const float* scb  = (const float*)d_in[7];
  const float* gw1  = (const float*)d_in[8];
  const float* gw2  = (const float*)d_in[9];
  const float* gw3  = (const float*)d_in[10];
  const float* l2w  = (const float*)d_in[11];
  const float* l2b  = (const float*)d_in[12];
  const float* tgm  = (const float*)d_in[13];

  short* wsh = (short*)d_ws;
  int N = in_sizes[0] / 1600;

  // prep: convert + transpose all weights to bf16 fragment layout (160 KiB)
  prep_weights_kernel<<<dim3(WS_SHORTS / 256), dim3(256), 0, stream>>>(
      l1w, l2w, scw, gw1, gw2, gw3, tgm, wsh);

  fused_sample_kernel<<<dim3(N), dim3(256), 0, stream>>>(
      x, nl0w, nl0b, affw, l1b, scb, l2b, wsh, (float*)d_out, N);
}

// Round 8
// 607.273 us; speedup vs baseline: 1.0164x; 1.0164x over previous
//
#include <hip/hip_runtime.h>
#include <hip/hip_bf16.h>

#define EPSV 1e-5f

typedef __attribute__((ext_vector_type(8))) short short8;
typedef __attribute__((ext_vector_type(4))) float f32x4;
typedef __attribute__((ext_vector_type(2))) unsigned int u32x2;

__device__ __forceinline__ int deg_of(int m) {
  return (m == 0) ? 0 : (m < 4 ? 1 : (m < 9 ? 2 : (m < 16 ? 3 : 4)));
}
__device__ __forceinline__ float silu_f(float v) { return v / (1.f + __expf(-v)); }
// round-to-nearest-even f32 -> bf16 bits (proven in rounds 0-2)
__device__ __forceinline__ unsigned short f2bf(float v) {
  unsigned int u = __float_as_uint(v);
  return (unsigned short)((u + 0x7FFFu + ((u >> 16) & 1u)) >> 16);
}
__device__ __forceinline__ short bfs(float v) { return (short)f2bf(v); }
// packed pair conversion built from the proven scalar path (low 16 = a, high 16 = b)
__device__ __forceinline__ unsigned int pk2(float a, float b) {
  return (unsigned int)f2bf(a) | ((unsigned int)f2bf(b) << 16);
}

// ---------------- workspace layout (shorts) ----------------
// l1T  [5][64 h][64 c]   @ 0       (20480)   l1T[l][h][c] = l1w[l][c][h]
// l2T  [5][64 o][64 h]   @ 20480   (20480)   l2T[l][o][h] = l2w[l][h][o]
// scT  [64 h][64 c]      @ 40960   (4096)    scT[h][c]    = scw[c][h]
// g1T  [128 o][64 h]     @ 45056   (8192)    g1T[o][h]    = gw1[h][o]
// g2T  [128 o][128 h]    @ 53248   (16384)   g2T[o][h]    = gw2[h][o]
// g3T  [64 o][128 h]     @ 69632   (8192)    g3T[o][h]    = gw3[h][o]
// tgP  [64 s][32 m]      @ 77824   (2048)    zero-padded m>=25
// tgT  [32 m][64 s]      @ 79872   (2048)    zero rows m>=25
#define OFF_L1 0
#define OFF_L2 20480
#define OFF_SC 40960
#define OFF_G1 45056
#define OFF_G2 53248
#define OFF_G3 69632
#define OFF_TG 77824
#define OFF_TGT 79872
#define WS_SHORTS 81920

__global__ __launch_bounds__(256) void prep_weights_kernel(
    const float* __restrict__ l1w, const float* __restrict__ l2w,
    const float* __restrict__ scw, const float* __restrict__ gw1,
    const float* __restrict__ gw2, const float* __restrict__ gw3,
    const float* __restrict__ tgm, short* __restrict__ wsh)
{
  int i = blockIdx.x * 256 + threadIdx.x;
  if (i < 20480) {                       // l1T
    int l = i >> 12, r = i & 4095, h = r >> 6, c = r & 63;
    wsh[i] = bfs(l1w[l * 4096 + c * 64 + h]);
  } else if (i < 40960) {                // l2T
    int r0 = i - OFF_L2;
    int l = r0 >> 12, r = r0 & 4095, o = r >> 6, h = r & 63;
    wsh[i] = bfs(l2w[l * 4096 + h * 64 + o]);
  } else if (i < 45056) {                // scT
    int r = i - OFF_SC, h = r >> 6, c = r & 63;
    wsh[i] = bfs(scw[c * 64 + h]);
  } else if (i < 53248) {                // g1T
    int r = i - OFF_G1, o = r >> 6, h = r & 63;
    wsh[i] = bfs(gw1[h * 128 + o]);
  } else if (i < 69632) {                // g2T
    int r = i - OFF_G2, o = r >> 7, h = r & 127;
    wsh[i] = bfs(gw2[h * 128 + o]);
  } else if (i < 77824) {                // g3T
    int r = i - OFF_G3, o = r >> 7, h = r & 127;
    wsh[i] = bfs(gw3[h * 64 + o]);
  } else if (i < 79872) {                // tgP [64][32], pad m>=25
    int r = i - OFF_TG, s = r >> 5, m = r & 31;
    wsh[i] = (m < 25) ? bfs(tgm[s * 25 + m]) : (short)0;
  } else if (i < WS_SHORTS) {            // tgT [32][64], zero rows m>=25
    int r = i - OFF_TGT, m = r >> 6, s = r & 63;
    wsh[i] = (m < 25) ? bfs(tgm[s * 25 + m]) : (short)0;
  }
}

// LDS layout (float indices), 9856 floats = 39,424 B -> 4 blocks/CU.
// Region A [0,4352):   XB f32 [25][68] (ph0-1b) -> T1u bf16 [64][136] (ph4-5)
//                      -> G3u bf16 [64][72] (ph6-7)
// Region B [4352,8704): XBh bf16 [32][72] @4352 (1b-3), H1u bf16 [64][40] @5504 (3-3b),
//                       GBu bf16 [64][72] @6784 (3b-4)  -> T2u bf16 [64][136] @4352 (5-6)
// Region C [8704,9856): RD f32 [256] (ph1) -> HBh bf16 [32][72] (ph7-8)
// (HBh rows 25..31 = floats 9604..9855: untouched between ph0 zeroing and ph8 reads)

__global__ __launch_bounds__(256, 4) void fused_sample_kernel(
    const float* __restrict__ x,
    const float* __restrict__ nl0w, const float* __restrict__ nl0b,
    const float* __restrict__ affw,
    const float* __restrict__ l1b,
    const float* __restrict__ scb,
    const float* __restrict__ l2b,
    const short* __restrict__ wsh,
    float* __restrict__ out, int nTot)
{
  __shared__ float sm[9856];
  float*          XB  = sm;                                   // [25][68] f32
  unsigned short* T1u = (unsigned short*)sm;                  // [64][136]
  unsigned short* G3u = (unsigned short*)sm;                  // [64][72]
  unsigned short* XBh = (unsigned short*)(sm + 4352);         // [32][72]
  unsigned short* H1u = (unsigned short*)(sm + 5504);         // [64][40]
  unsigned short* GBu = (unsigned short*)(sm + 6784);         // [64][72]
  unsigned short* T2u = (unsigned short*)(sm + 4352);         // [64][136]
  float*          RD  = sm + 8704;                            // [256]
  unsigned short* HBh = (unsigned short*)(sm + 8704);         // [32][72]

  const int t = threadIdx.x;
  const int n = blockIdx.x;
  if (n >= nTot) return;

  const int W    = t >> 6;
  const int lane = t & 63;
  const int quad = lane >> 4;
  const int l16  = lane & 15;
  const int hcol = W * 16 + l16;   // this wave's output column / row block

  const float* gx = x + (size_t)n * 1600;
  const short8 z8 = (short8){0,0,0,0,0,0,0,0};

  const short* l1T = wsh + OFF_L1;
  const short* l2T = wsh + OFF_L2;
  const short* scT = wsh + OFF_SC;
  const short* g1T = wsh + OFF_G1;
  const short* g2T = wsh + OFF_G2;
  const short* g3T = wsh + OFF_G3;
  const short* tgP = wsh + OFF_TG;
  const short* tgT = wsh + OFF_TGT;

  // ---- phase 0: stage x -> XB f32; zero all padding LDS regions ----
  for (int f = 4 * t; f < 1600; f += 1024) {
    float4 v = *(const float4*)(gx + f);
    int m = f >> 6, c = f & 63;
    *(float4*)(XB + m * 68 + c) = v;
  }
  for (int i = t; i < 448; i += 256) {       // H1u k-pad cols 25..31
    int r = i / 7, k = 25 + i % 7;
    H1u[r * 40 + k] = 0;
  }
  for (int i = t; i < 504; i += 256)         // XBh rows 25..31 (read by ph3 A-frags)
    XBh[25 * 72 + i] = 0;
  for (int i = t; i < 504; i += 256)         // HBh rows 25..31 (read by ph8 B-frags)
    HBh[25 * 72 + i] = 0;
  __syncthreads();

  // ---- phase 1: norms (float4-vectorized) ----
  {
    float part = 0.f;
    #pragma unroll
    for (int it = 0; it < 2; ++it) {
      int i = t + it * 256;
      if (i < 384) {
        int f = 64 + 4 * i;
        int m = f >> 6, c = f & 63;
        f32x4 v = *(const f32x4*)(XB + m * 68 + c);
        int l = deg_of(m);
        float w = 1.f / (float)((2 * l + 1) * 4);
        part += (v[0]*v[0] + v[1]*v[1] + v[2]*v[2] + v[3]*v[3]) * w;
      }
    }
    RD[t] = part;
  }
  __syncthreads();
  if (t < 64) {
    float s4 = RD[t] + RD[t + 64] + RD[t + 128] + RD[t + 192];
    #pragma unroll
    for (int o = 32; o >= 1; o >>= 1) s4 += __shfl_xor(s4, o, 64);
    if (t == 0) RD[0] = rsqrtf(s4 * (1.f / 64.f) + EPSV);
  } else if (t < 128) {
    int c = t - 64;
    float v = XB[c];
    float s1 = v, s2 = v * v;
    #pragma unroll
    for (int o = 32; o >= 1; o >>= 1) {
      s1 += __shfl_xor(s1, o, 64);
      s2 += __shfl_xor(s2, o, 64);
    }
    float mu  = s1 * (1.f / 64.f);
    float var = s2 * (1.f / 64.f) - mu * mu;
    XB[c] = (v - mu) * rsqrtf(var + EPSV) * nl0w[c] + nl0b[c];
  }
  __syncthreads();

  // ---- phase 1b: xn -> bf16 (XBh), float4 + pk2; PREFETCH ph3 weights ----
  short8 B3[12];  // [l*2+ks] for l1w, [10+ks] for scw
  {
    #pragma unroll
    for (int l = 0; l < 5; ++l)
      #pragma unroll
      for (int ks = 0; ks < 2; ++ks)
        B3[l * 2 + ks] = *(const short8*)(l1T + l * 4096 + hcol * 64 + ks * 32 + quad * 8);
    #pragma unroll
    for (int ks = 0; ks < 2; ++ks)
      B3[10 + ks] = *(const short8*)(scT + hcol * 64 + ks * 32 + quad * 8);

    float inv = RD[0];
    #pragma unroll
    for (int it = 0; it < 2; ++it) {
      int i = t + it * 256;
      if (i < 400) {
        int m = i >> 4, c = (i & 15) * 4;
        f32x4 v = *(const f32x4*)(XB + m * 68 + c);
        if (m > 0) {
          f32x4 aw = *(const f32x4*)(affw + (deg_of(m) - 1) * 64 + c);
          v[0] *= inv * aw[0]; v[1] *= inv * aw[1];
          v[2] *= inv * aw[2]; v[3] *= inv * aw[3];
        }
        u32x2 w; w[0] = pk2(v[0], v[1]); w[1] = pk2(v[2], v[3]);
        *(u32x2*)(XBh + m * 72 + c) = w;
      }
    }
  }
  __syncthreads();

  // ---- phase 3 (MFMA): h1 = xn @ lin1_w[deg]; gating row ----
  float gval;
  short8 tg3b;
  {
    tg3b = *(const short8*)(tgP + (W * 16 + l16) * 32 + quad * 8);

    short8 a0[2], a1[2];
    #pragma unroll
    for (int ks = 0; ks < 2; ++ks) {
      a0[ks] = *(const short8*)(XBh + l16 * 72 + ks * 32 + quad * 8);
      a1[ks] = *(const short8*)(XBh + (16 + l16) * 72 + ks * 32 + quad * 8);
    }
    const int dl = deg_of(l16);
    f32x4 c0 = (f32x4){0,0,0,0}, c1 = (f32x4){0,0,0,0}, cg = (f32x4){0,0,0,0};
    #pragma unroll
    for (int ks = 0; ks < 2; ++ks) {
      #pragma unroll
      for (int l = 0; l < 4; ++l) {
        short8 am = (dl == l) ? a0[ks] : z8;
        c0 = __builtin_amdgcn_mfma_f32_16x16x32_bf16(am, B3[l * 2 + ks], c0, 0, 0, 0);
      }
      c1 = __builtin_amdgcn_mfma_f32_16x16x32_bf16(a1[ks], B3[8 + ks], c1, 0, 0, 0);
      short8 ag = (l16 == 0) ? a0[ks] : z8;
      cg = __builtin_amdgcn_mfma_f32_16x16x32_bf16(ag, B3[10 + ks], cg, 0, 0, 0);
    }
    // D rows m = quad*4+r contiguous at H1u[hcol][m] -> packed b64 writes
    if (quad == 0) c0[0] += l1b[hcol];     // bias on m==0
    u32x2 w0; w0[0] = pk2(c0[0], c0[1]); w0[1] = pk2(c0[2], c0[3]);
    *(u32x2*)(H1u + hcol * 40 + quad * 4) = w0;
    if (quad < 2) {
      u32x2 w1; w1[0] = pk2(c1[0], c1[1]); w1[1] = pk2(c1[2], c1[3]);
      *(u32x2*)(H1u + hcol * 40 + 16 + quad * 4) = w1;
    } else if (quad == 2) {
      H1u[hcol * 40 + 24] = f2bf(c1[0]);   // m == 24
    }
    gval = silu_f(cg[0] + scb[hcol]);      // valid on quad==0 lanes
  }
  __syncthreads();

  // ---- phase 3b (MFMA, swapped): g^T = h1^T @ tg^T -> GBu[s][h]; PREFETCH ph4 ----
  short8 a4w[2][2];
  {
    #pragma unroll
    for (int nt2 = 0; nt2 < 2; ++nt2)
      #pragma unroll
      for (int ks = 0; ks < 2; ++ks)
        a4w[nt2][ks] = *(const short8*)(g1T + ((2 * W + nt2) * 16 + l16) * 64 + ks * 32 + quad * 8);

    f32x4 cg3[4];
    #pragma unroll
    for (int nt = 0; nt < 4; ++nt) cg3[nt] = (f32x4){0,0,0,0};
    #pragma unroll
    for (int nt = 0; nt < 4; ++nt) {
      short8 ah = *(const short8*)(H1u + (nt * 16 + l16) * 40 + quad * 8); // A: h1^T rows h
      cg3[nt] = __builtin_amdgcn_mfma_f32_16x16x32_bf16(ah, tg3b, cg3[nt], 0, 0, 0);
    }
    // D rows h = nt*16+quad*4+r contiguous at GBu[s = W*16+l16][h]
    #pragma unroll
    for (int nt = 0; nt < 4; ++nt) {
      u32x2 w; w[0] = pk2(cg3[nt][0], cg3[nt][1]); w[1] = pk2(cg3[nt][2], cg3[nt][3]);
      *(u32x2*)(GBu + (W * 16 + l16) * 72 + nt * 16 + quad * 4) = w;
    }
  }
  __syncthreads();

  // ---- phase 4 (MFMA, swapped): t1^T = gw1^T @ g^T -> T1u[s][o]; PREFETCH ph5 ----
  short8 a5w[2][4];
  {
    #pragma unroll
    for (int nt2 = 0; nt2 < 2; ++nt2)
      #pragma unroll
      for (int ks = 0; ks < 4; ++ks)
        a5w[nt2][ks] = *(const short8*)(g2T + ((2 * W + nt2) * 16 + l16) * 128 + ks * 32 + quad * 8);

    f32x4 acc[8];
    #pragma unroll
    for (int i = 0; i < 8; ++i) acc[i] = (f32x4){0,0,0,0};
    #pragma unroll
    for (int st = 0; st < 4; ++st)
      #pragma unroll
      for (int ks = 0; ks < 2; ++ks) {
        short8 b = *(const short8*)(GBu + (st * 16 + l16) * 72 + ks * 32 + quad * 8);
        acc[0 * 4 + st] = __builtin_amdgcn_mfma_f32_16x16x32_bf16(a4w[0][ks], b, acc[0 * 4 + st], 0, 0, 0);
        acc[1 * 4 + st] = __builtin_amdgcn_mfma_f32_16x16x32_bf16(a4w[1][ks], b, acc[1 * 4 + st], 0, 0, 0);
      }
    #pragma unroll
    for (int nt2 = 0; nt2 < 2; ++nt2)
      #pragma unroll
      for (int st = 0; st < 4; ++st) {
        f32x4 v = acc[nt2 * 4 + st];
        #pragma unroll
        for (int r = 0; r < 4; ++r) v[r] = silu_f(v[r]);
        u32x2 w; w[0] = pk2(v[0], v[1]); w[1] = pk2(v[2], v[3]);
        *(u32x2*)(T1u + (st * 16 + l16) * 136 + (2 * W + nt2) * 16 + quad * 4) = w;
      }
  }
  __syncthreads();

  // ---- phase 5 (MFMA, swapped): t2^T = gw2^T @ t1^T -> T2u[s][o]; PREFETCH ph6 ----
  short8 bf6[4];
  {
    #pragma unroll
    for (int ks = 0; ks < 4; ++ks)
      bf6[ks] = *(const short8*)(g3T + hcol * 128 + ks * 32 + quad * 8);

    f32x4 acc[8];
    #pragma unroll
    for (int i = 0; i < 8; ++i) acc[i] = (f32x4){0,0,0,0};
    #pragma unroll
    for (int st = 0; st < 4; ++st)
      #pragma unroll
      for (int ks = 0; ks < 4; ++ks) {
        short8 b = *(const short8*)(T1u + (st * 16 + l16) * 136 + ks * 32 + quad * 8);
        acc[0 * 4 + st] = __builtin_amdgcn_mfma_f32_16x16x32_bf16(a5w[0][ks], b, acc[0 * 4 + st], 0, 0, 0);
        acc[1 * 4 + st] = __builtin_amdgcn_mfma_f32_16x16x32_bf16(a5w[1][ks], b, acc[1 * 4 + st], 0, 0, 0);
      }
    #pragma unroll
    for (int nt2 = 0; nt2 < 2; ++nt2)
      #pragma unroll
      for (int st = 0; st < 4; ++st) {
        f32x4 v = acc[nt2 * 4 + st];
        #pragma unroll
        for (int r = 0; r < 4; ++r) v[r] = silu_f(v[r]);
        u32x2 w; w[0] = pk2(v[0], v[1]); w[1] = pk2(v[2], v[3]);
        *(u32x2*)(T2u + (st * 16 + l16) * 136 + (2 * W + nt2) * 16 + quad * 4) = w;
      }
  }
  __syncthreads();

  // ---- phase 6 (MFMA, unswapped): g3 = t2 @ gw3 -> G3u[h][s] packed; PREFETCH ph7 ----
  short8 b7w[2][2];
  {
    #pragma unroll
    for (int mt = 0; mt < 2; ++mt)
      #pragma unroll
      for (int ks = 0; ks < 2; ++ks)
        b7w[mt][ks] = *(const short8*)(tgT + (mt * 16 + l16) * 64 + ks * 32 + quad * 8);

    f32x4 acc[4];
    #pragma unroll
    for (int i = 0; i < 4; ++i) acc[i] = (f32x4){0,0,0,0};
    #pragma unroll
    for (int mt = 0; mt < 4; ++mt)
      #pragma unroll
      for (int ks = 0; ks < 4; ++ks) {
        short8 a = *(const short8*)(T2u + (mt * 16 + l16) * 136 + ks * 32 + quad * 8);
        acc[mt] = __builtin_amdgcn_mfma_f32_16x16x32_bf16(a, bf6[ks], acc[mt], 0, 0, 0);
      }
    // D rows s = mt*16+quad*4+r contiguous at G3u[hcol][s]
    #pragma unroll
    for (int mt = 0; mt < 4; ++mt) {
      u32x2 w; w[0] = pk2(acc[mt][0], acc[mt][1]); w[1] = pk2(acc[mt][2], acc[mt][3]);
      *(u32x2*)(G3u + hcol * 72 + mt * 16 + quad * 4) = w;
    }
  }
  __syncthreads();

  // ---- phase 7 (MFMA, swapped): hb^T = g3^T @ tg -> HBh[m][h]; PREFETCH ph8 ----
  short8 B8[10];
  {
    #pragma unroll
    for (int l = 0; l < 5; ++l)
      #pragma unroll
      for (int ks = 0; ks < 2; ++ks)
        B8[l * 2 + ks] = *(const short8*)(l2T + l * 4096 + hcol * 64 + ks * 32 + quad * 8);

    f32x4 c7[2];
    c7[0] = (f32x4){0,0,0,0}; c7[1] = (f32x4){0,0,0,0};
    #pragma unroll
    for (int ks = 0; ks < 2; ++ks) {
      short8 ag = *(const short8*)(G3u + hcol * 72 + ks * 32 + quad * 8);  // A: g3^T rows h
      c7[0] = __builtin_amdgcn_mfma_f32_16x16x32_bf16(ag, b7w[0][ks], c7[0], 0, 0, 0);
      c7[1] = __builtin_amdgcn_mfma_f32_16x16x32_bf16(ag, b7w[1][ks], c7[1], 0, 0, 0);
    }
    // D rows h = W*16+quad*4+r contiguous at HBh[m][h]; col m = mt*16+l16
    if (l16 >= 1) {                         // m in 1..15
      u32x2 w; w[0] = pk2(c7[0][0], c7[0][1]); w[1] = pk2(c7[0][2], c7[0][3]);
      *(u32x2*)(HBh + l16 * 72 + W * 16 + quad * 4) = w;
    }
    if (l16 < 9) {                          // m in 16..24
      u32x2 w; w[0] = pk2(c7[1][0], c7[1][1]); w[1] = pk2(c7[1][2], c7[1][3]);
      *(u32x2*)(HBh + (16 + l16) * 72 + W * 16 + quad * 4) = w;
    }
    if (quad == 0) HBh[hcol] = f2bf(gval);  // row m==0 = gating
  }
  __syncthreads();

  // ---- phase 8 (MFMA, swapped): out^T = l2^T @ hb^T, float4 global stores ----
  {
    short8 b0[2], b1[2];
    #pragma unroll
    for (int ks = 0; ks < 2; ++ks) {
      b0[ks] = *(const short8*)(HBh + l16 * 72 + ks * 32 + quad * 8);
      b1[ks] = *(const short8*)(HBh + (16 + l16) * 72 + ks * 32 + quad * 8);
    }
    const int dl = deg_of(l16);
    f32x4 c0 = (f32x4){0,0,0,0}, c1 = (f32x4){0,0,0,0};
    #pragma unroll
    for (int ks = 0; ks < 2; ++ks) {
      #pragma unroll
      for (int l = 0; l < 4; ++l) {
        short8 bm = (dl == l) ? b0[ks] : z8;   // zero B cols whose deg != l
        c0 = __builtin_amdgcn_mfma_f32_16x16x32_bf16(B8[l * 2 + ks], bm, c0, 0, 0, 0);
      }
      c1 = __builtin_amdgcn_mfma_f32_16x16x32_bf16(B8[8 + ks], b1[ks], c1, 0, 0, 0);
    }
    float* go = out + (size_t)n * 1600;
    // D rows o = W*16+quad*4+r contiguous -> float4 stores; col m = l16 (+16)
    if (l16 == 0) {
      f32x4 l2bv = *(const f32x4*)(l2b + W * 16 + quad * 4);
      c0[0] += l2bv[0]; c0[1] += l2bv[1]; c0[2] += l2bv[2]; c0[3] += l2bv[3];
    }
    *(f32x4*)(go + l16 * 64 + W * 16 + quad * 4) = c0;
    if (l16 < 9)
      *(f32x4*)(go + (16 + l16) * 64 + W * 16 + quad * 4) = c1;
  }
}

extern "C" void kernel_launch(void* const* d_in, const int* in_sizes, int n_in,
                              void* d_out, int out_size, void* d_ws, size_t ws_size,
                              hipStream_t stream) {
  const float* x    = (const float*)d_in[0];
  const float* nl0w = (const float*)d_in[1];
  const float* nl0b = (const float*)d_in[2];
  const float* affw = (const float*)d_in[3];
  const float* l1w  = (const float*)d_in[4];
  const float* l1b  = (const float*)d_in[5];
  const float* scw  = (const float*)d_in[6];
  const float* scb  = (const float*)d_in[7];
  const float* gw1  = (const float*)d_in[8];
  const float* gw2  = (const float*)d_in[9];
  const float* gw3  = (const float*)d_in[10];
  const float* l2w  = (const float*)d_in[11];
  const float* l2b  = (const float*)d_in[12];
  const float* tgm  = (const float*)d_in[13];

  short* wsh = (short*)d_ws;
  int N = in_sizes[0] / 1600;

  prep_weights_kernel<<<dim3(WS_SHORTS / 256), dim3(256), 0, stream>>>(
      l1w, l2w, scw, gw1, gw2, gw3, tgm, wsh);

  fused_sample_kernel<<<dim3(N), dim3(256), 0, stream>>>(
      x, nl0w, nl0b, affw, l1b, scb, l2b, wsh, (float*)d_out, N);
}

// Round 15
// 592.030 us; speedup vs baseline: 1.0426x; 1.0257x over previous
//
#include <hip/hip_runtime.h>
#include <hip/hip_bf16.h>

#define EPSV 1e-5f

typedef __attribute__((ext_vector_type(8))) short short8;
typedef __attribute__((ext_vector_type(4))) float f32x4;
typedef __attribute__((ext_vector_type(2))) unsigned int u32x2;

__device__ __forceinline__ int deg_of(int m) {
  return (m == 0) ? 0 : (m < 4 ? 1 : (m < 9 ? 2 : (m < 16 ? 3 : 4)));
}
// silu via raw v_rcp (1 ulp) instead of IEEE divide (~10 inst) — error << bf16 ulp
__device__ __forceinline__ float silu_f(float v) {
  return v * __builtin_amdgcn_rcpf(1.f + __expf(-v));
}
// round-to-nearest-even f32 -> bf16 bits (scalar, used in prep + 2 scalar spots)
__device__ __forceinline__ unsigned short f2bf(float v) {
  unsigned int u = __float_as_uint(v);
  return (unsigned short)((u + 0x7FFFu + ((u >> 16) & 1u)) >> 16);
}
__device__ __forceinline__ short bfs(float v) { return (short)f2bf(v); }
// packed pair conversion: +0x8000 round-half-up bias, then one v_perm_b32 packs
// high halves: dst = [bf16(a) | bf16(b)<<16]. 3 VALU ops vs ~9 for bit-twiddle.
__device__ __forceinline__ unsigned int pk2(float a, float b) {
  return __builtin_amdgcn_perm(__float_as_uint(b) + 0x8000u,
                               __float_as_uint(a) + 0x8000u, 0x07060302u);
}

// ---------------- workspace layout (shorts) ----------------
// l1T  [5][64 h][64 c]   @ 0       (20480)   l1T[l][h][c] = l1w[l][c][h]
// l2T  [5][64 o][64 h]   @ 20480   (20480)   l2T[l][o][h] = l2w[l][h][o]
// scT  [64 h][64 c]      @ 40960   (4096)    scT[h][c]    = scw[c][h]
// g1T  [128 o][64 h]     @ 45056   (8192)    g1T[o][h]    = gw1[h][o]
// g2T  [128 o][128 h]    @ 53248   (16384)   g2T[o][h]    = gw2[h][o]
// g3T  [64 o][128 h]     @ 69632   (8192)    g3T[o][h]    = gw3[h][o]
// tgP  [64 s][32 m]      @ 77824   (2048)    zero-padded m>=25
// tgT  [32 m][64 s]      @ 79872   (2048)    zero rows m>=25
#define OFF_L1 0
#define OFF_L2 20480
#define OFF_SC 40960
#define OFF_G1 45056
#define OFF_G2 53248
#define OFF_G3 69632
#define OFF_TG 77824
#define OFF_TGT 79872
#define WS_SHORTS 81920

__global__ __launch_bounds__(256) void prep_weights_kernel(
    const float* __restrict__ l1w, const float* __restrict__ l2w,
    const float* __restrict__ scw, const float* __restrict__ gw1,
    const float* __restrict__ gw2, const float* __restrict__ gw3,
    const float* __restrict__ tgm, short* __restrict__ wsh)
{
  int i = blockIdx.x * 256 + threadIdx.x;
  if (i < 20480) {                       // l1T
    int l = i >> 12, r = i & 4095, h = r >> 6, c = r & 63;
    wsh[i] = bfs(l1w[l * 4096 + c * 64 + h]);
  } else if (i < 40960) {                // l2T
    int r0 = i - OFF_L2;
    int l = r0 >> 12, r = r0 & 4095, o = r >> 6, h = r & 63;
    wsh[i] = bfs(l2w[l * 4096 + h * 64 + o]);
  } else if (i < 45056) {                // scT
    int r = i - OFF_SC, h = r >> 6, c = r & 63;
    wsh[i] = bfs(scw[c * 64 + h]);
  } else if (i < 53248) {                // g1T
    int r = i - OFF_G1, o = r >> 6, h = r & 63;
    wsh[i] = bfs(gw1[h * 128 + o]);
  } else if (i < 69632) {                // g2T
    int r = i - OFF_G2, o = r >> 7, h = r & 127;
    wsh[i] = bfs(gw2[h * 128 + o]);
  } else if (i < 77824) {                // g3T
    int r = i - OFF_G3, o = r >> 7, h = r & 127;
    wsh[i] = bfs(gw3[h * 64 + o]);
  } else if (i < 79872) {                // tgP [64][32], pad m>=25
    int r = i - OFF_TG, s = r >> 5, m = r & 31;
    wsh[i] = (m < 25) ? bfs(tgm[s * 25 + m]) : (short)0;
  } else if (i < WS_SHORTS) {            // tgT [32][64], zero rows m>=25
    int r = i - OFF_TGT, m = r >> 6, s = r & 63;
    wsh[i] = (m < 25) ? bfs(tgm[s * 25 + m]) : (short)0;
  }
}

// LDS layout (float indices), 9856 floats = 39,424 B -> 4 blocks/CU.
// Region A [0,4352):   XB f32 [25][68] (ph0-1b) -> T1u bf16 [64][136] (ph4-5)
//                      -> G3u bf16 [64][72] (ph6-7)
// Region B [4352,8704): XBh bf16 [32][72] @4352 (1b-3), H1u bf16 [64][40] @5504 (3-3b),
//                       GBu bf16 [64][72] @6784 (3b-4)  -> T2u bf16 [64][136] @4352 (5-6)
// Region C [8704,9856): RD f32 [256] (ph1) -> HBh bf16 [32][72] (ph7-8)
// (HBh rows 25..31 = floats 9604..9855: untouched between ph0 zeroing and ph8 reads)

__global__ __launch_bounds__(256, 4) void fused_sample_kernel(
    const float* __restrict__ x,
    const float* __restrict__ nl0w, const float* __restrict__ nl0b,
    const float* __restrict__ affw,
    const float* __restrict__ l1b,
    const float* __restrict__ scb,
    const float* __restrict__ l2b,
    const short* __restrict__ wsh,
    float* __restrict__ out, int nTot)
{
  __shared__ float sm[9856];
  float*          XB  = sm;                                   // [25][68] f32
  unsigned short* T1u = (unsigned short*)sm;                  // [64][136]
  unsigned short* G3u = (unsigned short*)sm;                  // [64][72]
  unsigned short* XBh = (unsigned short*)(sm + 4352);         // [32][72]
  unsigned short* H1u = (unsigned short*)(sm + 5504);         // [64][40]
  unsigned short* GBu = (unsigned short*)(sm + 6784);         // [64][72]
  unsigned short* T2u = (unsigned short*)(sm + 4352);         // [64][136]
  float*          RD  = sm + 8704;                            // [256]
  unsigned short* HBh = (unsigned short*)(sm + 8704);         // [32][72]

  const int t = threadIdx.x;
  const int n = blockIdx.x;
  if (n >= nTot) return;

  const int W    = t >> 6;
  const int lane = t & 63;
  const int quad = lane >> 4;
  const int l16  = lane & 15;
  const int hcol = W * 16 + l16;   // this wave's output column / row block

  const float* gx = x + (size_t)n * 1600;
  const short8 z8 = (short8){0,0,0,0,0,0,0,0};

  const short* l1T = wsh + OFF_L1;
  const short* l2T = wsh + OFF_L2;
  const short* scT = wsh + OFF_SC;
  const short* g1T = wsh + OFF_G1;
  const short* g2T = wsh + OFF_G2;
  const short* g3T = wsh + OFF_G3;
  const short* tgP = wsh + OFF_TG;
  const short* tgT = wsh + OFF_TGT;

  // ---- phase 0: stage x -> XB f32; zero all padding LDS regions ----
  for (int f = 4 * t; f < 1600; f += 1024) {
    float4 v = *(const float4*)(gx + f);
    int m = f >> 6, c = f & 63;
    *(float4*)(XB + m * 68 + c) = v;
  }
  for (int i = t; i < 448; i += 256) {       // H1u k-pad cols 25..31
    int r = i / 7, k = 25 + i % 7;
    H1u[r * 40 + k] = 0;
  }
  for (int i = t; i < 504; i += 256)         // XBh rows 25..31 (read by ph3 A-frags)
    XBh[25 * 72 + i] = 0;
  for (int i = t; i < 504; i += 256)         // HBh rows 25..31 (read by ph8 B-frags)
    HBh[25 * 72 + i] = 0;
  __syncthreads();

  // ---- phase 1: norms (float4-vectorized) ----
  {
    float part = 0.f;
    #pragma unroll
    for (int it = 0; it < 2; ++it) {
      int i = t + it * 256;
      if (i < 384) {
        int f = 64 + 4 * i;
        int m = f >> 6, c = f & 63;
        f32x4 v = *(const f32x4*)(XB + m * 68 + c);
        int l = deg_of(m);
        float w = 1.f / (float)((2 * l + 1) * 4);
        part += (v[0]*v[0] + v[1]*v[1] + v[2]*v[2] + v[3]*v[3]) * w;
      }
    }
    RD[t] = part;
  }
  __syncthreads();
  if (t < 64) {
    float s4 = RD[t] + RD[t + 64] + RD[t + 128] + RD[t + 192];
    #pragma unroll
    for (int o = 32; o >= 1; o >>= 1) s4 += __shfl_xor(s4, o, 64);
    if (t == 0) RD[0] = rsqrtf(s4 * (1.f / 64.f) + EPSV);
  } else if (t < 128) {
    int c = t - 64;
    float v = XB[c];
    float s1 = v, s2 = v * v;
    #pragma unroll
    for (int o = 32; o >= 1; o >>= 1) {
      s1 += __shfl_xor(s1, o, 64);
      s2 += __shfl_xor(s2, o, 64);
    }
    float mu  = s1 * (1.f / 64.f);
    float var = s2 * (1.f / 64.f) - mu * mu;
    XB[c] = (v - mu) * rsqrtf(var + EPSV) * nl0w[c] + nl0b[c];
  }
  __syncthreads();

  // ---- phase 1b: xn -> bf16 (XBh), float4 + pk2; PREFETCH ph3 weights ----
  short8 B3[12];  // [l*2+ks] for l1w, [10+ks] for scw
  {
    #pragma unroll
    for (int l = 0; l < 5; ++l)
      #pragma unroll
      for (int ks = 0; ks < 2; ++ks)
        B3[l * 2 + ks] = *(const short8*)(l1T + l * 4096 + hcol * 64 + ks * 32 + quad * 8);
    #pragma unroll
    for (int ks = 0; ks < 2; ++ks)
      B3[10 + ks] = *(const short8*)(scT + hcol * 64 + ks * 32 + quad * 8);

    float inv = RD[0];
    #pragma unroll
    for (int it = 0; it < 2; ++it) {
      int i = t + it * 256;
      if (i < 400) {
        int m = i >> 4, c = (i & 15) * 4;
        f32x4 v = *(const f32x4*)(XB + m * 68 + c);
        if (m > 0) {
          f32x4 aw = *(const f32x4*)(affw + (deg_of(m) - 1) * 64 + c);
          v[0] *= inv * aw[0]; v[1] *= inv * aw[1];
          v[2] *= inv * aw[2]; v[3] *= inv * aw[3];
        }
        u32x2 w; w[0] = pk2(v[0], v[1]); w[1] = pk2(v[2], v[3]);
        *(u32x2*)(XBh + m * 72 + c) = w;
      }
    }
  }
  __syncthreads();

  // ---- phase 3 (MFMA): h1 = xn @ lin1_w[deg]; gating row ----
  float gval;
  short8 tg3b;
  {
    tg3b = *(const short8*)(tgP + (W * 16 + l16) * 32 + quad * 8);

    short8 a0[2], a1[2];
    #pragma unroll
    for (int ks = 0; ks < 2; ++ks) {
      a0[ks] = *(const short8*)(XBh + l16 * 72 + ks * 32 + quad * 8);
      a1[ks] = *(const short8*)(XBh + (16 + l16) * 72 + ks * 32 + quad * 8);
    }
    const int dl = deg_of(l16);
    f32x4 c0 = (f32x4){0,0,0,0}, c1 = (f32x4){0,0,0,0}, cg = (f32x4){0,0,0,0};
    #pragma unroll
    for (int ks = 0; ks < 2; ++ks) {
      #pragma unroll
      for (int l = 0; l < 4; ++l) {
        short8 am = (dl == l) ? a0[ks] : z8;
        c0 = __builtin_amdgcn_mfma_f32_16x16x32_bf16(am, B3[l * 2 + ks], c0, 0, 0, 0);
      }
      c1 = __builtin_amdgcn_mfma_f32_16x16x32_bf16(a1[ks], B3[8 + ks], c1, 0, 0, 0);
      short8 ag = (l16 == 0) ? a0[ks] : z8;
      cg = __builtin_amdgcn_mfma_f32_16x16x32_bf16(ag, B3[10 + ks], cg, 0, 0, 0);
    }
    // D rows m = quad*4+r contiguous at H1u[hcol][m] -> packed b64 writes
    if (quad == 0) c0[0] += l1b[hcol];     // bias on m==0
    u32x2 w0; w0[0] = pk2(c0[0], c0[1]); w0[1] = pk2(c0[2], c0[3]);
    *(u32x2*)(H1u + hcol * 40 + quad * 4) = w0;
    if (quad < 2) {
      u32x2 w1; w1[0] = pk2(c1[0], c1[1]); w1[1] = pk2(c1[2], c1[3]);
      *(u32x2*)(H1u + hcol * 40 + 16 + quad * 4) = w1;
    } else if (quad == 2) {
      H1u[hcol * 40 + 24] = f2bf(c1[0]);   // m == 24
    }
    gval = silu_f(cg[0] + scb[hcol]);      // valid on quad==0 lanes
  }
  __syncthreads();

  // ---- phase 3b (MFMA, swapped): g^T = h1^T @ tg^T -> GBu[s][h]; PREFETCH ph4 ----
  short8 a4w[2][2];
  {
    #pragma unroll
    for (int nt2 = 0; nt2 < 2; ++nt2)
      #pragma unroll
      for (int ks = 0; ks < 2; ++ks)
        a4w[nt2][ks] = *(const short8*)(g1T + ((2 * W + nt2) * 16 + l16) * 64 + ks * 32 + quad * 8);

    f32x4 cg3[4];
    #pragma unroll
    for (int nt = 0; nt < 4; ++nt) cg3[nt] = (f32x4){0,0,0,0};
    #pragma unroll
    for (int nt = 0; nt < 4; ++nt) {
      short8 ah = *(const short8*)(H1u + (nt * 16 + l16) * 40 + quad * 8); // A: h1^T rows h
      cg3[nt] = __builtin_amdgcn_mfma_f32_16x16x32_bf16(ah, tg3b, cg3[nt], 0, 0, 0);
    }
    // D rows h = nt*16+quad*4+r contiguous at GBu[s = W*16+l16][h]
    #pragma unroll
    for (int nt = 0; nt < 4; ++nt) {
      u32x2 w; w[0] = pk2(cg3[nt][0], cg3[nt][1]); w[1] = pk2(cg3[nt][2], cg3[nt][3]);
      *(u32x2*)(GBu + (W * 16 + l16) * 72 + nt * 16 + quad * 4) = w;
    }
  }
  __syncthreads();

  // ---- phase 4 (MFMA, swapped): t1^T = gw1^T @ g^T -> T1u[s][o]; PREFETCH ph5 ----
  short8 a5w[2][4];
  {
    #pragma unroll
    for (int nt2 = 0; nt2 < 2; ++nt2)
      #pragma unroll
      for (int ks = 0; ks < 4; ++ks)
        a5w[nt2][ks] = *(const short8*)(g2T + ((2 * W + nt2) * 16 + l16) * 128 + ks * 32 + quad * 8);

    f32x4 acc[8];
    #pragma unroll
    for (int i = 0; i < 8; ++i) acc[i] = (f32x4){0,0,0,0};
    #pragma unroll
    for (int st = 0; st < 4; ++st)
      #pragma unroll
      for (int ks = 0; ks < 2; ++ks) {
        short8 b = *(const short8*)(GBu + (st * 16 + l16) * 72 + ks * 32 + quad * 8);
        acc[0 * 4 + st] = __builtin_amdgcn_mfma_f32_16x16x32_bf16(a4w[0][ks], b, acc[0 * 4 + st], 0, 0, 0);
        acc[1 * 4 + st] = __builtin_amdgcn_mfma_f32_16x16x32_bf16(a4w[1][ks], b, acc[1 * 4 + st], 0, 0, 0);
      }
    #pragma unroll
    for (int nt2 = 0; nt2 < 2; ++nt2)
      #pragma unroll
      for (int st = 0; st < 4; ++st) {
        f32x4 v = acc[nt2 * 4 + st];
        #pragma unroll
        for (int r = 0; r < 4; ++r) v[r] = silu_f(v[r]);
        u32x2 w; w[0] = pk2(v[0], v[1]); w[1] = pk2(v[2], v[3]);
        *(u32x2*)(T1u + (st * 16 + l16) * 136 + (2 * W + nt2) * 16 + quad * 4) = w;
      }
  }
  __syncthreads();

  // ---- phase 5 (MFMA, swapped): t2^T = gw2^T @ t1^T -> T2u[s][o]; PREFETCH ph6 ----
  short8 bf6[4];
  {
    #pragma unroll
    for (int ks = 0; ks < 4; ++ks)
      bf6[ks] = *(const short8*)(g3T + hcol * 128 + ks * 32 + quad * 8);

    f32x4 acc[8];
    #pragma unroll
    for (int i = 0; i < 8; ++i) acc[i] = (f32x4){0,0,0,0};
    #pragma unroll
    for (int st = 0; st < 4; ++st)
      #pragma unroll
      for (int ks = 0; ks < 4; ++ks) {
        short8 b = *(const short8*)(T1u + (st * 16 + l16) * 136 + ks * 32 + quad * 8);
        acc[0 * 4 + st] = __builtin_amdgcn_mfma_f32_16x16x32_bf16(a5w[0][ks], b, acc[0 * 4 + st], 0, 0, 0);
        acc[1 * 4 + st] = __builtin_amdgcn_mfma_f32_16x16x32_bf16(a5w[1][ks], b, acc[1 * 4 + st], 0, 0, 0);
      }
    #pragma unroll
    for (int nt2 = 0; nt2 < 2; ++nt2)
      #pragma unroll
      for (int st = 0; st < 4; ++st) {
        f32x4 v = acc[nt2 * 4 + st];
        #pragma unroll
        for (int r = 0; r < 4; ++r) v[r] = silu_f(v[r]);
        u32x2 w; w[0] = pk2(v[0], v[1]); w[1] = pk2(v[2], v[3]);
        *(u32x2*)(T2u + (st * 16 + l16) * 136 + (2 * W + nt2) * 16 + quad * 4) = w;
      }
  }
  __syncthreads();

  // ---- phase 6 (MFMA, unswapped): g3 = t2 @ gw3 -> G3u[h][s] packed; PREFETCH ph7 ----
  short8 b7w[2][2];
  {
    #pragma unroll
    for (int mt = 0; mt < 2; ++mt)
      #pragma unroll
      for (int ks = 0; ks < 2; ++ks)
        b7w[mt][ks] = *(const short8*)(tgT + (mt * 16 + l16) * 64 + ks * 32 + quad * 8);

    f32x4 acc[4];
    #pragma unroll
    for (int i = 0; i < 4; ++i) acc[i] = (f32x4){0,0,0,0};
    #pragma unroll
    for (int mt = 0; mt < 4; ++mt)
      #pragma unroll
      for (int ks = 0; ks < 4; ++ks) {
        short8 a = *(const short8*)(T2u + (mt * 16 + l16) * 136 + ks * 32 + quad * 8);
        acc[mt] = __builtin_amdgcn_mfma_f32_16x16x32_bf16(a, bf6[ks], acc[mt], 0, 0, 0);
      }
    // D rows s = mt*16+quad*4+r contiguous at G3u[hcol][s]
    #pragma unroll
    for (int mt = 0; mt < 4; ++mt) {
      u32x2 w; w[0] = pk2(acc[mt][0], acc[mt][1]); w[1] = pk2(acc[mt][2], acc[mt][3]);
      *(u32x2*)(G3u + hcol * 72 + mt * 16 + quad * 4) = w;
    }
  }
  __syncthreads();

  // ---- phase 7 (MFMA, swapped): hb^T = g3^T @ tg -> HBh[m][h]; PREFETCH ph8 ----
  short8 B8[10];
  {
    #pragma unroll
    for (int l = 0; l < 5; ++l)
      #pragma unroll
      for (int ks = 0; ks < 2; ++ks)
        B8[l * 2 + ks] = *(const short8*)(l2T + l * 4096 + hcol * 64 + ks * 32 + quad * 8);

    f32x4 c7[2];
    c7[0] = (f32x4){0,0,0,0}; c7[1] = (f32x4){0,0,0,0};
    #pragma unroll
    for (int ks = 0; ks < 2; ++ks) {
      short8 ag = *(const short8*)(G3u + hcol * 72 + ks * 32 + quad * 8);  // A: g3^T rows h
      c7[0] = __builtin_amdgcn_mfma_f32_16x16x32_bf16(ag, b7w[0][ks], c7[0], 0, 0, 0);
      c7[1] = __builtin_amdgcn_mfma_f32_16x16x32_bf16(ag, b7w[1][ks], c7[1], 0, 0, 0);
    }
    // D rows h = W*16+quad*4+r contiguous at HBh[m][h]; col m = mt*16+l16
    if (l16 >= 1) {                         // m in 1..15
      u32x2 w; w[0] = pk2(c7[0][0], c7[0][1]); w[1] = pk2(c7[0][2], c7[0][3]);
      *(u32x2*)(HBh + l16 * 72 + W * 16 + quad * 4) = w;
    }
    if (l16 < 9) {                          // m in 16..24
      u32x2 w; w[0] = pk2(c7[1][0], c7[1][1]); w[1] = pk2(c7[1][2], c7[1][3]);
      *(u32x2*)(HBh + (16 + l16) * 72 + W * 16 + quad * 4) = w;
    }
    if (quad == 0) HBh[hcol] = f2bf(gval);  // row m==0 = gating
  }
  __syncthreads();

  // ---- phase 8 (MFMA, swapped): out^T = l2^T @ hb^T, float4 global stores ----
  {
    short8 b0[2], b1[2];
    #pragma unroll
    for (int ks = 0; ks < 2; ++ks) {
      b0[ks] = *(const short8*)(HBh + l16 * 72 + ks * 32 + quad * 8);
      b1[ks] = *(const short8*)(HBh + (16 + l16) * 72 + ks * 32 + quad * 8);
    }
    const int dl = deg_of(l16);
    f32x4 c0 = (f32x4){0,0,0,0}, c1 = (f32x4){0,0,0,0};
    #pragma unroll
    for (int ks = 0; ks < 2; ++ks) {
      #pragma unroll
      for (int l = 0; l < 4; ++l) {
        short8 bm = (dl == l) ? b0[ks] : z8;   // zero B cols whose deg != l
        c0 = __builtin_amdgcn_mfma_f32_16x16x32_bf16(B8[l * 2 + ks], bm, c0, 0, 0, 0);
      }
      c1 = __builtin_amdgcn_mfma_f32_16x16x32_bf16(B8[8 + ks], b1[ks], c1, 0, 0, 0);
    }
    float* go = out + (size_t)n * 1600;
    // D rows o = W*16+quad*4+r contiguous -> float4 stores; col m = l16 (+16)
    if (l16 == 0) {
      f32x4 l2bv = *(const f32x4*)(l2b + W * 16 + quad * 4);
      c0[0] += l2bv[0]; c0[1] += l2bv[1]; c0[2] += l2bv[2]; c0[3] += l2bv[3];
    }
    *(f32x4*)(go + l16 * 64 + W * 16 + quad * 4) = c0;
    if (l16 < 9)
      *(f32x4*)(go + (16 + l16) * 64 + W * 16 + quad * 4) = c1;
  }
}

extern "C" void kernel_launch(void* const* d_in, const int* in_sizes, int n_in,
                              void* d_out, int out_size, void* d_ws, size_t ws_size,
                              hipStream_t stream) {
  const float* x    = (const float*)d_in[0];
  const float* nl0w = (const float*)d_in[1];
  const float* nl0b = (const float*)d_in[2];
  const float* affw = (const float*)d_in[3];
  const float* l1w  = (const float*)d_in[4];
  const float* l1b  = (const float*)d_in[5];
  const float* scw  = (const float*)d_in[6];
  const float* scb  = (const float*)d_in[7];
  const float* gw1  = (const float*)d_in[8];
  const float* gw2  = (const float*)d_in[9];
  const float* gw3  = (const float*)d_in[10];
  const float* l2w  = (const float*)d_in[11];
  const float* l2b  = (const float*)d_in[12];
  const float* tgm  = (const float*)d_in[13];

  short* wsh = (short*)d_ws;
  int N = in_sizes[0] / 1600;

  prep_weights_kernel<<<dim3(WS_SHORTS / 256), dim3(256), 0, stream>>>(
      l1w, l2w, scw, gw1, gw2, gw3, tgm, wsh);

  fused_sample_kernel<<<dim3(N), dim3(256), 0, stream>>>(
      x, nl0w, nl0b, affw, l1b, scb, l2b, wsh, (float*)d_out, N);
}